// Round 1
// 711.982 us; speedup vs baseline: 1.0092x; 1.0092x over previous
//
#include <hip/hip_runtime.h>
#include <hip/hip_bf16.h>
#include <stdint.h>

// Problem constants
#define BATCH 32
#define CIN   512
#define LLEN  4096
#define COUT  512
#define KW    3
#define KTOT  (CIN * KW)      // 1536
#define LPAD  (LLEN + 2)      // 4098 rows in qxT (zero row at 0 and 4097)
#define EPSQ  1e-8f

// GEMM geometry (256x256 tile, BK=32, 4-deep LDS ring, counted vmcnt)
#define BM 256
#define BN 256
#define BK 32
#define NT (KTOT / BK)        // 48 K-tiles
#define TILE_ELEMS (BM * BK)  // 8192 bf16 = 16 KiB per matrix per slot

typedef __bf16 bf16x8 __attribute__((ext_vector_type(8)));
typedef float  floatx4 __attribute__((ext_vector_type(4)));

__device__ __forceinline__ void async_load16(const void* gptr, void* ldsptr) {
    __builtin_amdgcn_global_load_lds(
        (const __attribute__((address_space(1))) void*)gptr,
        (__attribute__((address_space(3))) void*)ldsptr,
        16, 0, 0);
}

// ---------------------------------------------------------------------------
// Kernel 1: zero the two padding rows (l = -1 and l = LLEN) of qxT per batch.
__global__ void zero_pad_kernel(uint32_t* __restrict__ qxT_u32) {
    int idx = blockIdx.x * blockDim.x + threadIdx.x;   // 0..16383
    int b = idx >> 9;
    int r = (idx >> 8) & 1;
    int c = idx & 255;
    size_t row = (size_t)b * LPAD + (r ? (LPAD - 1) : 0);
    qxT_u32[row * (CIN / 2) + c] = 0u;
}

// ---------------------------------------------------------------------------
// Kernel 2: quantize x per C_in channel and transpose to qxT[b][l+1][i], bf16.
__global__ __launch_bounds__(256) void quantx_kernel(
        const float* __restrict__ x,
        const float* __restrict__ a_scale,
        __bf16* __restrict__ qxT) {
    __shared__ __bf16 qs[64][66];   // [l][i], pad -> low-conflict
    const int i0 = blockIdx.x * 64;
    const int l0 = blockIdx.y * 64;
    const int b  = blockIdx.z;
    const int tid = threadIdx.x;

    const int f4   = tid & 15;
    const int irow = tid >> 4;     // 0..15
    #pragma unroll
    for (int p = 0; p < 4; ++p) {
        int i = p * 16 + irow;
        float s = fabsf(a_scale[i0 + i]) + EPSQ;
        float inv = 1.0f / s;                         // exact, once per channel
        const floatx4* xrow = (const floatx4*)(x + ((size_t)(b * CIN + i0 + i)) * LLEN + l0);
        floatx4 v = xrow[f4];
        #pragma unroll
        for (int j = 0; j < 4; ++j) {
            float q = fminf(fmaxf(rintf(v[j] * inv), -128.0f), 127.0f);
            qs[f4 * 4 + j][i] = (__bf16)q;
        }
    }
    __syncthreads();

    const int c4 = tid & 15;       // 4-channel group
    const int rr = tid >> 4;       // 0..15
    uint2* outp = (uint2*)(qxT + ((size_t)b * LPAD + (l0 + 1)) * CIN + i0);
    #pragma unroll
    for (int p = 0; p < 4; ++p) {
        int l = p * 16 + rr;
        const uint32_t* qrow = (const uint32_t*)&qs[l][0];
        uint2 u;
        u.x = qrow[2 * c4];
        u.y = qrow[2 * c4 + 1];
        outp[(size_t)l * (CIN / 4) + c4] = u;
    }
}

// ---------------------------------------------------------------------------
// Kernel 3: fold weights: Wf[o][k*512+i] = clip(round(w/sw)) * sa * sw (bf16)
__global__ void wfold_kernel(
        const float* __restrict__ w,
        const float* __restrict__ a_scale,
        const float* __restrict__ w_scale,
        __bf16* __restrict__ Wf) {
    int idx = blockIdx.x * blockDim.x + threadIdx.x;
    if (idx >= COUT * KTOT) return;
    int o   = idx / KTOT;
    int rem = idx - o * KTOT;
    int k = rem >> 9;
    int i = rem & 511;
    float sw = fabsf(w_scale[o]) + EPSQ;
    float sa = fabsf(a_scale[i]) + EPSQ;
    float q = fminf(fmaxf(rintf(w[((size_t)o * CIN + i) * KW + k] / sw), -128.0f), 127.0f);
    Wf[idx] = (__bf16)(q * sa * sw);
}

// ---------------------------------------------------------------------------
// Kernel 4: deep-pipelined GEMM.
// 256x256 tile, BK=32, 4-slot LDS ring (128 KiB), 3 tiles prefetched ahead,
// counted s_waitcnt vmcnt(12) (never 0 in steady state), raw s_barrier,
// XOR-swizzled staging (linear LDS dst + swizzled global src + same XOR on
// ds_read_b128), setprio around the MFMA cluster, bijective XCD swizzle.
// 8 waves: wave-tile 128(o) x 64(l); acc[8][4] f32x4.
__global__ __launch_bounds__(512, 2) void qconv_gemm(
        const __bf16* __restrict__ Wf,
        const __bf16* __restrict__ qxT,
        const float* __restrict__ bias,
        float* __restrict__ out) {
    __shared__ __attribute__((aligned(16))) __bf16 As[4][TILE_ELEMS];
    __shared__ __attribute__((aligned(16))) __bf16 Bs[4][TILE_ELEMS];

    const int tid = threadIdx.x;

    // XCD-aware bijective chunk swizzle: nwg = 2*16*32 = 1024, 8 XCDs, q=128.
    // Each XCD gets 128 consecutive logical tiles = 4 complete batches.
    int flat = blockIdx.x + gridDim.x * (blockIdx.y + gridDim.y * blockIdx.z);
    int logical = (flat & 7) * 128 + (flat >> 3);
    const int m0 = (logical & 1) * BM;          // o-tile: 0 or 256
    const int l0 = ((logical >> 1) & 15) * BN;  // l-tile: 0..3840
    const int b  = logical >> 5;                // batch

    const int wave  = tid >> 6;
    const int lane  = tid & 63;
    const int wm    = wave >> 2;    // 0..1 -> 128 o rows each
    const int wn    = wave & 3;     // 0..3 -> 64 l cols each
    const int row16 = lane & 15;
    const int quad  = lane >> 4;

    const __bf16* qxb = qxT + (size_t)b * LPAD * CIN;

    floatx4 acc[8][4];
    #pragma unroll
    for (int mt = 0; mt < 8; ++mt)
        #pragma unroll
        for (int nt = 0; nt < 4; ++nt)
            acc[mt][nt] = (floatx4){0.f, 0.f, 0.f, 0.f};

    // Staging chunk map: chunk c (16B) -> row = c>>2, stored global col-chunk
    // g = (c&3) ^ (row&3). LDS destination stays lane-linear (rule #21).
    const int ca0 = tid,        ca1 = 512 + tid;
    const int ra0 = ca0 >> 2,   ra1 = ca1 >> 2;
    const int ga0 = (ca0 & 3) ^ (ra0 & 3);
    const int ga1 = (ca1 & 3) ^ (ra1 & 3);
    const __bf16* aptr0 = Wf  + (size_t)(m0 + ra0) * KTOT + ga0 * 8;
    const __bf16* aptr1 = Wf  + (size_t)(m0 + ra1) * KTOT + ga1 * 8;
    const __bf16* bptr0 = qxb + (size_t)(l0 + ra0) * CIN  + ga0 * 8;
    const __bf16* bptr1 = qxb + (size_t)(l0 + ra1) * CIN  + ga1 * 8;

    // issue order per tile: A0, A1, B0, B1  (4 vmem ops -> vmcnt accounting)
    auto STAGE = [&](int t) {
        const int kk0  = t * BK;         // element offset into Wf row
        const int kblk = kk0 >> 9;       // conv tap (BK never straddles a tap)
        const int i0   = kk0 & 511;
        const int slot = t & 3;
        char* abase = (char*)&As[slot][0];
        char* bbase = (char*)&Bs[slot][0];
        async_load16(aptr0 + kk0,                        abase + ca0 * 16);
        async_load16(aptr1 + kk0,                        abase + ca1 * 16);
        async_load16(bptr0 + (size_t)kblk * CIN + i0,    bbase + ca0 * 16);
        async_load16(bptr1 + (size_t)kblk * CIN + i0,    bbase + ca1 * 16);
    };

    // prologue: 3 tiles in flight (12 loads)
    STAGE(0); STAGE(1); STAGE(2);

    for (int t = 0; t < NT; ++t) {
        // B1: all waves finished reading slot (t-1)&3 == (t+3)&3 last iter,
        // so it is safe to start overwriting it.
        __builtin_amdgcn_sched_barrier(0);
        __builtin_amdgcn_s_barrier();
        __builtin_amdgcn_sched_barrier(0);

        if (t + 3 < NT) STAGE(t + 3);

        // wait for MY tile-t loads (issued 3 iters ago); in-order vmcnt
        // semantics make this correct even if unrelated loads interleave.
        if (t < NT - 3)      asm volatile("s_waitcnt vmcnt(12)" ::: "memory");
        else if (t == NT-3)  asm volatile("s_waitcnt vmcnt(8)"  ::: "memory");
        else if (t == NT-2)  asm volatile("s_waitcnt vmcnt(4)"  ::: "memory");
        else                 asm volatile("s_waitcnt vmcnt(0)"  ::: "memory");

        // B2: everyone's tile-t staging is complete -> LDS tile visible.
        __builtin_amdgcn_sched_barrier(0);
        __builtin_amdgcn_s_barrier();
        __builtin_amdgcn_sched_barrier(0);

        const int slot = t & 3;
        const __bf16* Ab = &As[slot][0];
        const __bf16* Bb = &Bs[slot][0];

        bf16x8 af[8], bfr[4];
        #pragma unroll
        for (int mt = 0; mt < 8; ++mt) {
            int arow = wm * 128 + mt * 16 + row16;
            int js   = quad ^ (arow & 3);
            af[mt] = *(const bf16x8*)(Ab + arow * BK + js * 8);
        }
        #pragma unroll
        for (int nt = 0; nt < 4; ++nt) {
            int brow = wn * 64 + nt * 16 + row16;
            int js   = quad ^ (brow & 3);
            bfr[nt] = *(const bf16x8*)(Bb + brow * BK + js * 8);
        }

        __builtin_amdgcn_s_setprio(1);
        #pragma unroll
        for (int mt = 0; mt < 8; ++mt)
            #pragma unroll
            for (int nt = 0; nt < 4; ++nt)
                acc[mt][nt] = __builtin_amdgcn_mfma_f32_16x16x32_bf16(
                    af[mt], bfr[nt], acc[mt][nt], 0, 0, 0);
        __builtin_amdgcn_s_setprio(0);
    }

    // epilogue: C/D layout col=lane&15 (n=l), row=quad*4+reg (m=o)
    float* outb = out + ((size_t)b * COUT + m0) * LLEN;
    #pragma unroll
    for (int mt = 0; mt < 8; ++mt) {
        #pragma unroll
        for (int r = 0; r < 4; ++r) {
            int o = wm * 128 + mt * 16 + quad * 4 + r;
            float bv = bias[m0 + o];
            #pragma unroll
            for (int nt = 0; nt < 4; ++nt) {
                int l = l0 + wn * 64 + nt * 16 + row16;
                outb[(size_t)o * LLEN + l] = acc[mt][nt][r] + bv;
            }
        }
    }
}

// ---------------------------------------------------------------------------
extern "C" void kernel_launch(void* const* d_in, const int* in_sizes, int n_in,
                              void* d_out, int out_size, void* d_ws, size_t ws_size,
                              hipStream_t stream) {
    const float* x       = (const float*)d_in[0];
    const float* weight  = (const float*)d_in[1];
    const float* bias    = (const float*)d_in[2];
    const float* a_scale = (const float*)d_in[3];
    const float* w_scale = (const float*)d_in[4];
    float* out = (float*)d_out;

    __bf16* Wf  = (__bf16*)d_ws;
    __bf16* qxT = (__bf16*)((char*)d_ws + (size_t)COUT * KTOT * sizeof(__bf16));

    wfold_kernel<<<dim3((COUT * KTOT) / 256), dim3(256), 0, stream>>>(
        weight, a_scale, w_scale, Wf);
    zero_pad_kernel<<<dim3(64), dim3(256), 0, stream>>>((uint32_t*)qxT);
    quantx_kernel<<<dim3(CIN / 64, LLEN / 64, BATCH), dim3(256), 0, stream>>>(
        x, a_scale, qxT);
    qconv_gemm<<<dim3(COUT / BM, LLEN / BN, BATCH), dim3(512), 0, stream>>>(
        Wf, qxT, bias, out);
}

// Round 2
// 644.272 us; speedup vs baseline: 1.1153x; 1.1051x over previous
//
#include <hip/hip_runtime.h>
#include <hip/hip_bf16.h>
#include <stdint.h>

// Problem constants
#define BATCH 32
#define CIN   512
#define LLEN  4096
#define COUT  512
#define KW    3
#define KTOT  (CIN * KW)      // 1536
#define LPAD  (LLEN + 2)      // 4098 rows in qxT (zero row at 0 and 4097)
#define EPSQ  1e-8f

// GEMM geometry: 256x256 tile, BK=64, 2-slot dbuf, 8-phase schedule (m201 port)
#define BM 256
#define BN 256
#define BK 64
#define NTILES (KTOT / BK)    // 24 K-tiles
#define NI (NTILES / 2)       // 12 outer iters (2 K-tiles each)
#define SLOT_ELEMS (BM * BK)  // 16384 bf16 = 32 KiB per matrix per slot

typedef __bf16 bf16x8 __attribute__((ext_vector_type(8)));
typedef float  floatx4 __attribute__((ext_vector_type(4)));

__device__ __forceinline__ void async_load16(const void* gptr, void* ldsptr) {
    __builtin_amdgcn_global_load_lds(
        (const __attribute__((address_space(1))) void*)gptr,
        (__attribute__((address_space(3))) void*)ldsptr,
        16, 0, 0);
}

// ---------------------------------------------------------------------------
// Kernel 1: zero the two padding rows (l = -1 and l = LLEN) of qxT per batch.
__global__ void zero_pad_kernel(uint32_t* __restrict__ qxT_u32) {
    int idx = blockIdx.x * blockDim.x + threadIdx.x;   // 0..16383
    int b = idx >> 9;
    int r = (idx >> 8) & 1;
    int c = idx & 255;
    size_t row = (size_t)b * LPAD + (r ? (LPAD - 1) : 0);
    qxT_u32[row * (CIN / 2) + c] = 0u;
}

// ---------------------------------------------------------------------------
// Kernel 2: quantize x per C_in channel and transpose to qxT[b][l+1][i], bf16.
__global__ __launch_bounds__(256) void quantx_kernel(
        const float* __restrict__ x,
        const float* __restrict__ a_scale,
        __bf16* __restrict__ qxT) {
    __shared__ __bf16 qs[64][66];   // [l][i], pad -> low-conflict
    const int i0 = blockIdx.x * 64;
    const int l0 = blockIdx.y * 64;
    const int b  = blockIdx.z;
    const int tid = threadIdx.x;

    const int f4   = tid & 15;
    const int irow = tid >> 4;     // 0..15
    #pragma unroll
    for (int p = 0; p < 4; ++p) {
        int i = p * 16 + irow;
        float s = fabsf(a_scale[i0 + i]) + EPSQ;
        float inv = 1.0f / s;                         // exact, once per channel
        const floatx4* xrow = (const floatx4*)(x + ((size_t)(b * CIN + i0 + i)) * LLEN + l0);
        floatx4 v = xrow[f4];
        #pragma unroll
        for (int j = 0; j < 4; ++j) {
            float q = fminf(fmaxf(rintf(v[j] * inv), -128.0f), 127.0f);
            qs[f4 * 4 + j][i] = (__bf16)q;
        }
    }
    __syncthreads();

    const int c4 = tid & 15;       // 4-channel group
    const int rr = tid >> 4;       // 0..15
    uint2* outp = (uint2*)(qxT + ((size_t)b * LPAD + (l0 + 1)) * CIN + i0);
    #pragma unroll
    for (int p = 0; p < 4; ++p) {
        int l = p * 16 + rr;
        const uint32_t* qrow = (const uint32_t*)&qs[l][0];
        uint2 u;
        u.x = qrow[2 * c4];
        u.y = qrow[2 * c4 + 1];
        outp[(size_t)l * (CIN / 4) + c4] = u;
    }
}

// ---------------------------------------------------------------------------
// Kernel 3: fold weights: Wf[o][k*512+i] = clip(round(w/sw)) * sa * sw (bf16)
__global__ void wfold_kernel(
        const float* __restrict__ w,
        const float* __restrict__ a_scale,
        const float* __restrict__ w_scale,
        __bf16* __restrict__ Wf) {
    int idx = blockIdx.x * blockDim.x + threadIdx.x;
    if (idx >= COUT * KTOT) return;
    int o   = idx / KTOT;
    int rem = idx - o * KTOT;
    int k = rem >> 9;
    int i = rem & 511;
    float sw = fabsf(w_scale[o]) + EPSQ;
    float sa = fabsf(a_scale[i]) + EPSQ;
    float q = fminf(fmaxf(rintf(w[((size_t)o * CIN + i) * KW + k] / sw), -128.0f), 127.0f);
    Wf[idx] = (__bf16)(q * sa * sw);
}

// ---------------------------------------------------------------------------
// Kernel 4: 8-phase deep-pipelined GEMM (m201 template port).
// BK=64 rows are 8x16B chunks; XOR-swizzle chunk col with (row&7) -> 2-way
// (free) bank aliasing on ds_read_b128. Stage via global_load_lds with
// pre-swizzled GLOBAL source + lane-linear LDS dest (rule #21).
// Per outer iter: 8 phases, each {ds_reads, 1 half-stage (2 loads), barrier,
// lgkmcnt(0), setprio, 16 MFMA, setprio, barrier}; vmcnt(2) at end of
// phases 4 and 8 only (loads stay in flight across barriers).
//
// Conv-as-GEMM note: B offset (l0+row+kblk)*CIN + i0 collapses to
// (l0+row)*CIN + tau*64 because kblk*CIN + i0 == tau*64. Taps are free.

#define BARR() do { __builtin_amdgcn_sched_barrier(0); \
                    __builtin_amdgcn_s_barrier();      \
                    __builtin_amdgcn_sched_barrier(0); } while (0)
#define LGKM0() do { asm volatile("s_waitcnt lgkmcnt(0)" ::: "memory"); \
                     __builtin_amdgcn_sched_barrier(0); } while (0)
#define VMW(n) do { asm volatile("s_waitcnt vmcnt(" #n ")" ::: "memory"); \
                    __builtin_amdgcn_sched_barrier(0); } while (0)

// stage half: matrix M in {A,B}, tile tau, load-slot q (chunks q*512+tid)
#define STG_A(tau, q) async_load16(Wf  + aoff[q] + (tau) * 64, \
        (char*)&As[(tau) & 1][0] + doff[q])
#define STG_B(tau, q) async_load16(qxb + boff[q] + (tau) * 64, \
        (char*)&Bs[(tau) & 1][0] + doff[q])

// read A-frag half qm (8 x ds_read_b128) from slot pointer Ab
#define RD_AF(Ab, qm) do { \
    _Pragma("unroll") for (int mti = 0; mti < 4; ++mti) { \
        _Pragma("unroll") for (int ks = 0; ks < 2; ++ks) { \
            int arow = wm * 128 + ((qm) * 4 + mti) * 16 + row16; \
            int js   = (ks * 4 + quad) ^ (arow & 7); \
            af[mti][ks] = *(const bf16x8*)((Ab) + arow * 64 + js * 8); \
        } } } while (0)

// read B-frag half qn (4 x ds_read_b128) into dst from slot pointer Bb
#define RD_BF(Bb, dst, qn) do { \
    _Pragma("unroll") for (int nti = 0; nti < 2; ++nti) { \
        _Pragma("unroll") for (int ks = 0; ks < 2; ++ks) { \
            int brow = wn * 64 + ((qn) * 2 + nti) * 16 + row16; \
            int js   = (ks * 4 + quad) ^ (brow & 7); \
            dst[nti][ks] = *(const bf16x8*)((Bb) + brow * 64 + js * 8); \
        } } } while (0)

// 16 MFMA: quadrant (qm,qn) over K=64 (both ks accumulate into same acc)
#define MFMAQ(qm, qn, bsrc) do { \
    __builtin_amdgcn_s_setprio(1); \
    _Pragma("unroll") for (int mti = 0; mti < 4; ++mti) { \
        _Pragma("unroll") for (int nti = 0; nti < 2; ++nti) { \
            _Pragma("unroll") for (int ks = 0; ks < 2; ++ks) { \
                acc[(qm) * 4 + mti][(qn) * 2 + nti] = \
                    __builtin_amdgcn_mfma_f32_16x16x32_bf16( \
                        af[mti][ks], bsrc[nti][ks], \
                        acc[(qm) * 4 + mti][(qn) * 2 + nti], 0, 0, 0); \
            } } } \
    __builtin_amdgcn_s_setprio(0); } while (0)

__global__ __launch_bounds__(512, 2) void qconv_gemm(
        const __bf16* __restrict__ Wf,
        const __bf16* __restrict__ qxT,
        const float* __restrict__ bias,
        float* __restrict__ out) {
    __shared__ __attribute__((aligned(16))) __bf16 As[2][SLOT_ELEMS];
    __shared__ __attribute__((aligned(16))) __bf16 Bs[2][SLOT_ELEMS];

    const int tid = threadIdx.x;

    // XCD-aware bijective chunk swizzle: nwg=1024, 8 XCDs, 128 tiles/XCD.
    int flat = blockIdx.x + gridDim.x * (blockIdx.y + gridDim.y * blockIdx.z);
    int logical = (flat & 7) * 128 + (flat >> 3);
    const int m0 = (logical & 1) * BM;
    const int l0 = ((logical >> 1) & 15) * BN;
    const int b  = logical >> 5;

    const int wave  = tid >> 6;
    const int lane  = tid & 63;
    const int wm    = wave >> 2;    // 0..1 -> 128 o-rows
    const int wn    = wave & 3;     // 0..3 -> 64 l-cols
    const int row16 = lane & 15;
    const int quad  = lane >> 4;

    const __bf16* qxb = qxT + (size_t)b * LPAD * CIN;

    floatx4 acc[8][4];
    #pragma unroll
    for (int mt = 0; mt < 8; ++mt)
        #pragma unroll
        for (int nt = 0; nt < 4; ++nt)
            acc[mt][nt] = (floatx4){0.f, 0.f, 0.f, 0.f};

    // Per-thread staging constants. Chunk id c = q*512 + tid; row = c>>3,
    // local col = c&7, global col g = (c&7)^(row&7) (XOR involution).
    int aoff[4], boff[4], doff[4];
    #pragma unroll
    for (int q = 0; q < 4; ++q) {
        int c = q * 512 + tid;
        int r = c >> 3;
        int g = (c & 7) ^ (r & 7);
        aoff[q] = (m0 + r) * KTOT + g * 8;
        boff[q] = (l0 + r) * CIN  + g * 8;
        doff[q] = c * 16;
    }

    bf16x8 af[4][2], bf0[2][2], bf1[2][2];

    // Prologue: tile0 fully + tile1 A-lo = 10 loads; drain tile0, keep 2.
    STG_A(0, 0); STG_A(0, 1); STG_A(0, 2); STG_A(0, 3);
    STG_B(0, 0); STG_B(0, 1); STG_B(0, 2); STG_B(0, 3);
    STG_A(1, 0); STG_A(1, 1);
    VMW(2);
    BARR();

    for (int i = 0; i < NI; ++i) {
        const int t1 = 2 * i + 1, t2 = 2 * i + 2, t3 = 2 * i + 3;
        const __bf16* Ab0 = &As[0][0];
        const __bf16* Bb0 = &Bs[0][0];
        const __bf16* Ab1 = &As[1][0];
        const __bf16* Bb1 = &Bs[1][0];
        const bool more = (i + 1 < NI);

        // P1: tile t0 quadrant (0,0); stage A-hi(t1)
        RD_BF(Bb0, bf0, 0); RD_AF(Ab0, 0);
        STG_A(t1, 2); STG_A(t1, 3);
        BARR(); LGKM0();
        MFMAQ(0, 0, bf0);
        BARR();

        // P2: quadrant (0,1); stage B-lo(t1)
        RD_BF(Bb0, bf1, 1);
        STG_B(t1, 0); STG_B(t1, 1);
        BARR(); LGKM0();
        MFMAQ(0, 1, bf1);
        BARR();

        // P3: quadrant (1,1); stage B-hi(t1)
        RD_AF(Ab0, 1);
        STG_B(t1, 2); STG_B(t1, 3);
        BARR(); LGKM0();
        MFMAQ(1, 1, bf1);
        BARR();

        // P4: quadrant (1,0) (reuses bf0 from P1, af from P3); stage A-lo(t2)
        if (more) { STG_A(t2, 0); STG_A(t2, 1); }
        BARR(); LGKM0();
        MFMAQ(1, 0, bf0);
        if (more) { VMW(2); } else { VMW(0); }   // drain tile t1 -> slot1 ready
        BARR();

        // P5: tile t1 quadrant (0,0); stage A-hi(t2)
        RD_BF(Bb1, bf0, 0); RD_AF(Ab1, 0);
        if (more) { STG_A(t2, 2); STG_A(t2, 3); }
        BARR(); LGKM0();
        MFMAQ(0, 0, bf0);
        BARR();

        // P6: quadrant (0,1); stage B-lo(t2)
        RD_BF(Bb1, bf1, 1);
        if (more) { STG_B(t2, 0); STG_B(t2, 1); }
        BARR(); LGKM0();
        MFMAQ(0, 1, bf1);
        BARR();

        // P7: quadrant (1,1); stage B-hi(t2)
        RD_AF(Ab1, 1);
        if (more) { STG_B(t2, 2); STG_B(t2, 3); }
        BARR(); LGKM0();
        MFMAQ(1, 1, bf1);
        BARR();

        // P8: quadrant (1,0); stage A-lo(t3); drain tile t2 -> slot0 ready
        if (more) { STG_A(t3, 0); STG_A(t3, 1); }
        BARR(); LGKM0();
        MFMAQ(1, 0, bf0);
        VMW(2);
        BARR();
    }

    // Epilogue: C/D layout col=lane&15 (n=l), row=quad*4+reg (m=o)
    float* outb = out + ((size_t)b * COUT + m0) * LLEN;
    #pragma unroll
    for (int mt = 0; mt < 8; ++mt) {
        #pragma unroll
        for (int r = 0; r < 4; ++r) {
            int o = wm * 128 + mt * 16 + quad * 4 + r;
            float bv = bias[m0 + o];
            #pragma unroll
            for (int nt = 0; nt < 4; ++nt) {
                int l = l0 + wn * 64 + nt * 16 + row16;
                outb[(size_t)o * LLEN + l] = acc[mt][nt][r] + bv;
            }
        }
    }
}

// ---------------------------------------------------------------------------
extern "C" void kernel_launch(void* const* d_in, const int* in_sizes, int n_in,
                              void* d_out, int out_size, void* d_ws, size_t ws_size,
                              hipStream_t stream) {
    const float* x       = (const float*)d_in[0];
    const float* weight  = (const float*)d_in[1];
    const float* bias    = (const float*)d_in[2];
    const float* a_scale = (const float*)d_in[3];
    const float* w_scale = (const float*)d_in[4];
    float* out = (float*)d_out;

    __bf16* Wf  = (__bf16*)d_ws;
    __bf16* qxT = (__bf16*)((char*)d_ws + (size_t)COUT * KTOT * sizeof(__bf16));

    wfold_kernel<<<dim3((COUT * KTOT) / 256), dim3(256), 0, stream>>>(
        weight, a_scale, w_scale, Wf);
    zero_pad_kernel<<<dim3(64), dim3(256), 0, stream>>>((uint32_t*)qxT);
    quantx_kernel<<<dim3(CIN / 64, LLEN / 64, BATCH), dim3(256), 0, stream>>>(
        x, a_scale, qxT);
    qconv_gemm<<<dim3(COUT / BM, LLEN / BN, BATCH), dim3(512), 0, stream>>>(
        Wf, qxT, bias, out);
}